// Round 6
// baseline (4994.814 us; speedup 1.0000x reference)
//
#include <hip/hip_runtime.h>

// HyMBA block, MI355X — ROUND 6: output stored as FLOAT32 (reference output
// dtype). Inputs proven f32-stored (round-2-vs-5 A/B). Pipeline semantics
// identical to round 5 (all-VALU correctness anchor).

#define MROWS 16384   // B*N rows
#define SEQ   2048

__device__ __forceinline__ float bf2f(unsigned short u) {
    union { unsigned int i; float f; } c; c.i = ((unsigned int)u) << 16; return c.f;
}
__device__ __forceinline__ unsigned short f2bf(float f) {
    union { float f; unsigned int i; } c; c.f = f;
    unsigned int x = c.i;
    return (unsigned short)((x + 0x7fffu + ((x >> 16) & 1u)) >> 16);
}
// dual-dtype scalar input load
__device__ __forceinline__ float ldin(const void* p, size_t i, int isf32) {
    return isf32 ? ((const float*)p)[i] : bf2f(((const unsigned short*)p)[i]);
}
__device__ __forceinline__ float sigf(float v) { return 1.f / (1.f + __expf(-v)); }
__device__ __forceinline__ float tanhf_fast(float v) { return 2.f * sigf(2.f * v) - 1.f; }

// ---- input dtype sniff: bf16 N(0,1) data never has exponent byte >= 0xC0;
// fp32-underlying half-words hit that ~25% of the time.
__global__ void sniff_kernel(const unsigned short* __restrict__ x, int* __restrict__ flag) {
    int tid = threadIdx.x;  // 64 threads
    int big = 0;
    for (int i = tid; i < 1024; i += 64) {
        unsigned int e = (x[i] >> 7) & 0xFFu;
        big += (e >= 0xC0u) ? 1 : 0;
    }
#pragma unroll
    for (int off = 32; off; off >>= 1) big += __shfl_down(big, off);
    if (tid == 0) *flag = (big >= 4) ? 1 : 0;
}

// sentinel: zero-fill d_out as f32
__global__ void zero_out_kernel(float* __restrict__ out) {
    size_t i = ((size_t)blockIdx.x * 256 + threadIdx.x) * 16;
#pragma unroll
    for (int u = 0; u < 16; u++) out[i + u] = 0.f;
}

// ---------------- VALU GEMM: 64x64 tile, BK=16, 256 threads, 4x4/thread ----------------
__device__ __forceinline__ void stage_valu(const void* __restrict__ g, int ld, int row0,
                                           int kb, float (*lds)[68], int tid, int isf32) {
#pragma unroll
    for (int u = 0; u < 4; u++) {
        int idx = tid * 4 + u;          // [0,1024)
        int row = idx >> 4;             // [0,64)
        int k = idx & 15;               // [0,16)
        lds[k][row] = ldin(g, (size_t)(row0 + row) * ld + kb + k, isf32);
    }
}

__device__ __forceinline__ void fma_tile(const float (*As)[68], const float (*Bs)[68],
                                         int tx, int ty, float (*acc)[4]) {
#pragma unroll
    for (int k = 0; k < 16; k++) {
        float4 av = *reinterpret_cast<const float4*>(&As[k][ty * 4]);
        float4 bv = *reinterpret_cast<const float4*>(&Bs[k][tx * 4]);
        float a[4] = {av.x, av.y, av.z, av.w};
        float b[4] = {bv.x, bv.y, bv.z, bv.w};
#pragma unroll
        for (int i = 0; i < 4; i++)
#pragma unroll
            for (int j = 0; j < 4; j++) acc[i][j] = fmaf(a[i], b[j], acc[i][j]);
    }
}

// C[M,N] = A[M,K] * W[N,K]^T + bias[N]; bf16 out (internal staging only).
__global__ __launch_bounds__(256) void gemm_valu_kernel(
    const void* __restrict__ A, const void* __restrict__ W,
    const void* __restrict__ bias, unsigned short* __restrict__ C,
    int N, int K, const int* __restrict__ flagp) {
    __shared__ __align__(16) float As[16][68];
    __shared__ __align__(16) float Bs[16][68];
    int isf32 = *flagp;
    int tid = threadIdx.x, tx = tid & 15, ty = tid >> 4;
    int tileM = blockIdx.x << 6, tileN = blockIdx.y << 6;
    float acc[4][4];
#pragma unroll
    for (int i = 0; i < 4; i++)
#pragma unroll
        for (int j = 0; j < 4; j++) acc[i][j] = 0.f;

    for (int kb = 0; kb < K; kb += 16) {
        __syncthreads();
        stage_valu(A, K, tileM, kb, As, tid, isf32);
        stage_valu(W, K, tileN, kb, Bs, tid, isf32);
        __syncthreads();
        fma_tile(As, Bs, tx, ty, acc);
    }
#pragma unroll
    for (int i = 0; i < 4; i++) {
        int row = tileM + ty * 4 + i;
#pragma unroll
        for (int j = 0; j < 4; j++) {
            int col = tileN + tx * 4 + j;
            float v = acc[i][j] + ldin(bias, col, isf32);
            C[(size_t)row * N + col] = f2bf(v);
        }
    }
}

// gx[row][2] = sigmoid(x_row . gate_w[g] + gate_b[g]); one wave per row
__global__ __launch_bounds__(256) void gate_kernel(
    const void* __restrict__ x, const void* __restrict__ gw,
    const void* __restrict__ gb, float* __restrict__ gx, const int* __restrict__ flagp) {
    int isf32 = *flagp;
    int row = (blockIdx.x << 2) + (threadIdx.x >> 6);
    int lane = threadIdx.x & 63;
    size_t xoff = (size_t)row * 1024 + lane * 16;
    float a0 = 0.f, a1 = 0.f;
#pragma unroll
    for (int q = 0; q < 2; q++) {
#pragma unroll
        for (int e = 0; e < 8; e++) {
            size_t k = q * 8 + e;
            float xf = ldin(x, xoff + k, isf32);
            a0 += xf * ldin(gw, (size_t)lane * 16 + k, isf32);
            a1 += xf * ldin(gw, 1024 + (size_t)lane * 16 + k, isf32);
        }
    }
#pragma unroll
    for (int off = 32; off > 0; off >>= 1) {
        a0 += __shfl_down(a0, off);
        a1 += __shfl_down(a1, off);
    }
    if (lane == 0) {
        gx[row * 2]     = sigf(a0 + ldin(gb, 0, isf32));
        gx[row * 2 + 1] = sigf(a1 + ldin(gb, 1, isf32));
    }
}

// Sequential scans. blocks 0..7: GRU (batch=blockIdx), blocks 8..15: SSM (batch-8).
__global__ __launch_bounds__(384) void scan_kernel(
    const void* __restrict__ Amat,            // [64][64]   input dtype
    const void* __restrict__ Whh,             // [384][128] input dtype
    const void* __restrict__ bhh,             // [384]      input dtype
    const unsigned short* __restrict__ bxw,   // [MROWS][64]  bf16
    const unsigned short* __restrict__ ihw,   // [MROWS][384] bf16
    unsigned short* __restrict__ hsw,         // [MROWS][64]  bf16
    unsigned short* __restrict__ hrw,         // [MROWS][128] bf16
    const int* __restrict__ flagp) {
    int isf32 = *flagp;
    int b = blockIdx.x & 7;
    int o = threadIdx.x;
    size_t rowbase = (size_t)b * SEQ;

    if (blockIdx.x < 8) {
        // ---------------- GRU ----------------
        __shared__ __align__(16) float h[128];
        __shared__ float hhb[384];
        __shared__ float ihb[384];
        float W[128];
#pragma unroll
        for (int j = 0; j < 128; j++) W[j] = ldin(Whh, (size_t)o * 128 + j, isf32);
        float bias = ldin(bhh, o, isf32);
        if (o < 128) h[o] = 0.f;
        float iv_c = bf2f(ihw[rowbase * 384 + o]);
        float iv_n = bf2f(ihw[(rowbase + 1) * 384 + o]);
        __syncthreads();
        for (int t = 0; t < SEQ; t++) {
            float iv_f = 0.f;
            if (t + 2 < SEQ) iv_f = bf2f(ihw[(rowbase + t + 2) * 384 + o]);
            float s0 = bias, s1 = 0.f, s2 = 0.f, s3 = 0.f;
            const float4* h4 = reinterpret_cast<const float4*>(h);
#pragma unroll
            for (int j = 0; j < 32; j++) {
                float4 hv = h4[j];
                s0 += W[4 * j]     * hv.x;
                s1 += W[4 * j + 1] * hv.y;
                s2 += W[4 * j + 2] * hv.z;
                s3 += W[4 * j + 3] * hv.w;
            }
            hhb[o] = (s0 + s1) + (s2 + s3);
            ihb[o] = iv_c;
            __syncthreads();
            if (o < 128) {
                float r  = sigf(ihb[o] + hhb[o]);
                float zg = sigf(ihb[128 + o] + hhb[128 + o]);
                float n  = tanhf_fast(ihb[256 + o] + r * hhb[256 + o]);
                float hnew = (1.f - zg) * n + zg * h[o];
                h[o] = hnew;
                hrw[(rowbase + t) * 128 + o] = f2bf(hnew);
            }
            __syncthreads();
            iv_c = iv_n; iv_n = iv_f;
        }
    } else {
        // ---------------- SSM ----------------
        __shared__ __align__(16) float hs[64];
        bool act = (o < 64);
        float Arow[64];
        float bx_c = 0.f, bx_n = 0.f;
        if (act) {
#pragma unroll
            for (int j = 0; j < 64; j++) Arow[j] = ldin(Amat, (size_t)o * 64 + j, isf32);
            hs[o] = 0.f;
            bx_c = bf2f(bxw[rowbase * 64 + o]);
            bx_n = bf2f(bxw[(rowbase + 1) * 64 + o]);
        }
        __syncthreads();
        for (int t = 0; t < SEQ; t++) {
            float bx_f = 0.f;
            float s0 = 0.f, s1 = 0.f, s2 = 0.f, s3 = 0.f;
            if (act) {
                if (t + 2 < SEQ) bx_f = bf2f(bxw[(rowbase + t + 2) * 64 + o]);
                const float4* h4 = reinterpret_cast<const float4*>(hs);
#pragma unroll
                for (int j = 0; j < 16; j++) {
                    float4 hv = h4[j];
                    s0 += Arow[4 * j]     * hv.x;
                    s1 += Arow[4 * j + 1] * hv.y;
                    s2 += Arow[4 * j + 2] * hv.z;
                    s3 += Arow[4 * j + 3] * hv.w;
                }
            }
            __syncthreads();
            if (act) {
                float v = (s0 + s1) + (s2 + s3) + bx_c;
                float hval = v * sigf(v);             // silu
                hs[o] = hval;
                hsw[(rowbase + t) * 64 + o] = f2bf(hval);
            }
            __syncthreads();
            bx_c = bx_n; bx_n = bx_f;
        }
    }
}

// out[row,col] = g0*(x.Dw^T + hs.Cw^T + Cb + Db) + g1*(hr.pw^T + pb)  — f32 store
__global__ __launch_bounds__(256) void out_valu_kernel(
    const void* __restrict__ x,  const void* __restrict__ Dw, const void* __restrict__ Db,
    const unsigned short* __restrict__ hs, const void* __restrict__ Cw, const void* __restrict__ Cb,
    const unsigned short* __restrict__ hr, const void* __restrict__ pw, const void* __restrict__ pb,
    const float* __restrict__ gx, float* __restrict__ out,
    const int* __restrict__ flagp) {
    __shared__ __align__(16) float As[16][68];
    __shared__ __align__(16) float Bs[16][68];
    int isf32 = *flagp;
    int tid = threadIdx.x, tx = tid & 15, ty = tid >> 4;
    int tileM = blockIdx.x << 6, tileN = blockIdx.y << 6;
    float acc1[4][4], acc2[4][4];
#pragma unroll
    for (int i = 0; i < 4; i++)
#pragma unroll
        for (int j = 0; j < 4; j++) { acc1[i][j] = 0.f; acc2[i][j] = 0.f; }

    for (int kb = 0; kb < 1024; kb += 16) {        // x . Dw^T (K=1024)
        __syncthreads();
        stage_valu(x,  1024, tileM, kb, As, tid, isf32);
        stage_valu(Dw, 1024, tileN, kb, Bs, tid, isf32);
        __syncthreads();
        fma_tile(As, Bs, tx, ty, acc1);
    }
    for (int kb = 0; kb < 64; kb += 16) {          // + hs . Cw^T (K=64), same acc
        __syncthreads();
        stage_valu(hs, 64, tileM, kb, As, tid, 0);
        stage_valu(Cw, 64, tileN, kb, Bs, tid, isf32);
        __syncthreads();
        fma_tile(As, Bs, tx, ty, acc1);
    }
    for (int kb = 0; kb < 128; kb += 16) {         // hr . pw^T (K=128)
        __syncthreads();
        stage_valu(hr, 128, tileM, kb, As, tid, 0);
        stage_valu(pw, 128, tileN, kb, Bs, tid, isf32);
        __syncthreads();
        fma_tile(As, Bs, tx, ty, acc2);
    }
#pragma unroll
    for (int i = 0; i < 4; i++) {
        int row = tileM + ty * 4 + i;
        float g0 = gx[row * 2], g1 = gx[row * 2 + 1];
#pragma unroll
        for (int j = 0; j < 4; j++) {
            int col = tileN + tx * 4 + j;
            float cb  = ldin(Cb, col, isf32) + ldin(Db, col, isf32);
            float pbv = ldin(pb, col, isf32);
            float v = g0 * (acc1[i][j] + cb) + g1 * (acc2[i][j] + pbv);
            out[(size_t)row * 1024 + col] = v;       // FLOAT32 store
        }
    }
}

extern "C" void kernel_launch(void* const* d_in, const int* in_sizes, int n_in,
                              void* d_out, int out_size, void* d_ws, size_t ws_size,
                              hipStream_t stream) {
    static const int expect_sizes[16] = {16777216, 4096, 65536, 64, 65536, 1024,
                                         1048576, 1024, 393216, 384, 49152, 384,
                                         131072, 1024, 2048, 2};
    bool order_ok = (n_in == 16);
    if (order_ok)
        for (int i = 0; i < 16; i++)
            if (in_sizes[i] != expect_sizes[i]) { order_ok = false; break; }
    float* out = (float*)d_out;
    if (!order_ok) {
        zero_out_kernel<<<dim3(4096), dim3(256), 0, stream>>>(out);
        return;
    }

    const void* x    = d_in[0];
    const void* Amat = d_in[1];
    const void* Bw   = d_in[2];
    const void* Bb   = d_in[3];
    const void* Cw   = d_in[4];
    const void* Cb   = d_in[5];
    const void* Dw   = d_in[6];
    const void* Db   = d_in[7];
    const void* Wih  = d_in[8];
    const void* bih  = d_in[9];
    const void* Whh  = d_in[10];
    const void* bhh  = d_in[11];
    const void* pw   = d_in[12];
    const void* pb   = d_in[13];
    const void* gw   = d_in[14];
    const void* gb   = d_in[15];

    // ALL staging in d_ws (21.1 MB): flag | gx | hs | hr | bx | ih
    char* ws = (char*)d_ws;
    int*            flg = (int*)(ws);                        //       256 B
    float*          gxw = (float*)(ws + 256);                //   131,072 B
    unsigned short* hsw = (unsigned short*)(ws + 131328);    // 2,097,152 B
    unsigned short* hrw = (unsigned short*)(ws + 2228480);   // 4,194,304 B
    unsigned short* bxw = (unsigned short*)(ws + 6422784);   // 2,097,152 B
    unsigned short* ihw = (unsigned short*)(ws + 8519936);   // 12,582,912 B  (end: 21,102,848)

    dim3 blk(256);
    sniff_kernel<<<dim3(1), dim3(64), 0, stream>>>((const unsigned short*)x, flg);
    // phase 1: input projections (VALU GEMMs, into d_ws)
    gemm_valu_kernel<<<dim3(256, 6), blk, 0, stream>>>(x, Wih, bih, ihw, 384, 1024, flg);
    gemm_valu_kernel<<<dim3(256, 1), blk, 0, stream>>>(x, Bw, Bb, bxw, 64, 1024, flg);
    gate_kernel<<<dim3(4096), blk, 0, stream>>>(x, gw, gb, gxw, flg);
    // phase 2: sequential scans (8 GRU + 8 SSM workgroups)
    scan_kernel<<<dim3(16), dim3(384), 0, stream>>>(Amat, Whh, bhh, bxw, ihw, hsw, hrw, flg);
    // phase 3: fused gated output projection (includes x.Dw^T), f32 output
    out_valu_kernel<<<dim3(256, 16), blk, 0, stream>>>(x, Dw, Db, hsw, Cw, Cb, hrw, pw, pb, gxw, out, flg);
}

// Round 7
// 2314.496 us; speedup vs baseline: 2.1581x; 2.1581x over previous
//
#include <hip/hip_runtime.h>

// HyMBA block, MI355X — ROUND 7: MFMA everywhere.
// phase1: ih/bx MFMA GEMMs + gate. phase2: scans with MFMA matvec
// (GRU: 4 waves, Whh fragments in VGPRs, 24 MFMA/step, 1 barrier/step;
//  SSM: 1 wave, 8 MFMA/step, no barrier). phase3: fused out GEMM, f32 store.
// Inputs f32 (runtime-sniffed dual path kept), output f32.

#define MROWS 16384   // B*N rows
#define SEQ   2048

typedef __attribute__((ext_vector_type(8))) short bf16x8;
typedef __attribute__((ext_vector_type(4))) float f32x4;

__device__ __forceinline__ float bf2f(unsigned short u) {
    union { unsigned int i; float f; } c; c.i = ((unsigned int)u) << 16; return c.f;
}
__device__ __forceinline__ unsigned short f2bf(float f) {
    union { float f; unsigned int i; } c; c.f = f;
    unsigned int x = c.i;
    return (unsigned short)((x + 0x7fffu + ((x >> 16) & 1u)) >> 16);
}
__device__ __forceinline__ float ldin(const void* p, size_t i, int isf32) {
    return isf32 ? ((const float*)p)[i] : bf2f(((const unsigned short*)p)[i]);
}
__device__ __forceinline__ float sigf(float v) { return 1.f / (1.f + __expf(-v)); }
__device__ __forceinline__ float tanhf_fast(float v) { return 2.f * sigf(2.f * v) - 1.f; }

__global__ void sniff_kernel(const unsigned short* __restrict__ x, int* __restrict__ flag) {
    int tid = threadIdx.x;
    int big = 0;
    for (int i = tid; i < 1024; i += 64) {
        unsigned int e = (x[i] >> 7) & 0xFFu;
        big += (e >= 0xC0u) ? 1 : 0;
    }
#pragma unroll
    for (int off = 32; off; off >>= 1) big += __shfl_down(big, off);
    if (tid == 0) *flag = (big >= 4) ? 1 : 0;
}

__global__ void zero_out_kernel(float* __restrict__ out) {
    size_t i = ((size_t)blockIdx.x * 256 + threadIdx.x) * 16;
#pragma unroll
    for (int u = 0; u < 16; u++) out[i + u] = 0.f;
}

// ---------------- MFMA GEMM: 128x128 tile, BK=32, 256 threads ----------------
__device__ __forceinline__ void stage_tile(const void* __restrict__ g,
                                           int ld, int row0, int rowmax, int kb,
                                           short (*lds)[40], int tid, int isf32) {
#pragma unroll
    for (int q = 0; q < 2; q++) {
        int oct = q * 256 + tid;
        int row = oct >> 2, c8 = (oct & 3) << 3;
        int gr = row0 + row; if (gr > rowmax) gr = rowmax;
        size_t base = (size_t)gr * ld + kb + c8;
        bf16x8 v;
        if (isf32) {
            const float* gp = (const float*)g + base;
            float4 f0 = *reinterpret_cast<const float4*>(gp);
            float4 f1 = *reinterpret_cast<const float4*>(gp + 4);
            v[0] = (short)f2bf(f0.x); v[1] = (short)f2bf(f0.y);
            v[2] = (short)f2bf(f0.z); v[3] = (short)f2bf(f0.w);
            v[4] = (short)f2bf(f1.x); v[5] = (short)f2bf(f1.y);
            v[6] = (short)f2bf(f1.z); v[7] = (short)f2bf(f1.w);
        } else {
            v = *reinterpret_cast<const bf16x8*>((const unsigned short*)g + base);
        }
        *reinterpret_cast<bf16x8*>(&lds[row][c8]) = v;
    }
}

// A-frag: m=lane&15, k=(lane>>4)*8+j ; B-frag: n=lane&15 (W stored [n][k]).
// C/D: col=lane&15, row=(lane>>4)*4+reg   [m89-verified]
__device__ __forceinline__ void mfma_tiles(const short (*As)[40], const short (*Bs)[40],
                                           int wm, int wn, int lane, f32x4 (*acc)[4]) {
    bf16x8 af[4], bfr[4];
    int m = lane & 15, ko = (lane >> 4) << 3;
#pragma unroll
    for (int i = 0; i < 4; i++)
        af[i] = *reinterpret_cast<const bf16x8*>(&As[wm + i * 16 + m][ko]);
#pragma unroll
    for (int j = 0; j < 4; j++)
        bfr[j] = *reinterpret_cast<const bf16x8*>(&Bs[wn + j * 16 + m][ko]);
#pragma unroll
    for (int i = 0; i < 4; i++)
#pragma unroll
        for (int j = 0; j < 4; j++)
            acc[i][j] = __builtin_amdgcn_mfma_f32_16x16x32_bf16(af[i], bfr[j], acc[i][j], 0, 0, 0);
}

// C[M,N] = A[M,K]*W[N,K]^T + bias[N]; bf16 staging out
__global__ __launch_bounds__(256) void gemm_bt_kernel(
    const void* __restrict__ A, const void* __restrict__ W,
    const void* __restrict__ bias, unsigned short* __restrict__ C,
    int M, int N, int K, const int* __restrict__ flagp) {
    __shared__ __align__(16) short As[128][40];
    __shared__ __align__(16) short Bs[128][40];
    int isf32 = *flagp;
    int tid = threadIdx.x, lane = tid & 63, wave = tid >> 6;
    int wm = (wave >> 1) << 6, wn = (wave & 1) << 6;
    int tileM = blockIdx.x << 7, tileN = blockIdx.y << 7;
    f32x4 acc[4][4];
    f32x4 z = {0.f, 0.f, 0.f, 0.f};
#pragma unroll
    for (int i = 0; i < 4; i++)
#pragma unroll
        for (int j = 0; j < 4; j++) acc[i][j] = z;

    for (int kb = 0; kb < K; kb += 32) {
        __syncthreads();
        stage_tile(A, K, tileM, M - 1, kb, As, tid, isf32);
        stage_tile(W, K, tileN, N - 1, kb, Bs, tid, isf32);
        __syncthreads();
        mfma_tiles(As, Bs, wm, wn, lane, acc);
    }
#pragma unroll
    for (int i = 0; i < 4; i++) {
#pragma unroll
        for (int j = 0; j < 4; j++) {
            int col = tileN + wn + j * 16 + (lane & 15);
            if (col < N) {
                float bv = ldin(bias, col, isf32);
                int row0 = tileM + wm + i * 16 + ((lane >> 4) << 2);
#pragma unroll
                for (int r = 0; r < 4; r++)
                    C[(size_t)(row0 + r) * N + col] = f2bf(acc[i][j][r] + bv);
            }
        }
    }
}

// gx[row][2] = sigmoid(x_row . gate_w[g] + gate_b[g])
__global__ __launch_bounds__(256) void gate_kernel(
    const void* __restrict__ x, const void* __restrict__ gw,
    const void* __restrict__ gb, float* __restrict__ gx, const int* __restrict__ flagp) {
    int isf32 = *flagp;
    int row = (blockIdx.x << 2) + (threadIdx.x >> 6);
    int lane = threadIdx.x & 63;
    size_t xoff = (size_t)row * 1024 + lane * 16;
    float a0 = 0.f, a1 = 0.f;
#pragma unroll
    for (int q = 0; q < 2; q++) {
#pragma unroll
        for (int e = 0; e < 8; e++) {
            size_t k = q * 8 + e;
            float xf = ldin(x, xoff + k, isf32);
            a0 += xf * ldin(gw, (size_t)lane * 16 + k, isf32);
            a1 += xf * ldin(gw, 1024 + (size_t)lane * 16 + k, isf32);
        }
    }
#pragma unroll
    for (int off = 32; off > 0; off >>= 1) {
        a0 += __shfl_down(a0, off);
        a1 += __shfl_down(a1, off);
    }
    if (lane == 0) {
        gx[row * 2]     = sigf(a0 + ldin(gb, 0, isf32));
        gx[row * 2 + 1] = sigf(a1 + ldin(gb, 1, isf32));
    }
}

// ---------------- MFMA sequential scans ----------------
// blocks 0..7: GRU (batch b). 256 thr = 4 waves; wave w owns n-tiles {w+4l}
// so (r,z,n) triples for o-tiles j=w and j=w+4 are in-wave. A = h (row 0 of a
// [16][128] bf16 LDS tile, rows 1-15 zero), double-buffered -> 1 barrier/step.
// blocks 8..15: SSM, wave 0 only, same structure, no barrier.
__global__ __launch_bounds__(256) void scan_kernel(
    const void* __restrict__ Amat,            // [64][64]
    const void* __restrict__ Whh,             // [384][128]
    const void* __restrict__ bhh,             // [384]
    const unsigned short* __restrict__ bxw,   // [MROWS][64]  bf16 (Bb included)
    const unsigned short* __restrict__ ihw,   // [MROWS][384] bf16 (b_ih included)
    unsigned short* __restrict__ hsw,         // [MROWS][64]
    unsigned short* __restrict__ hrw,         // [MROWS][128]
    const int* __restrict__ flagp) {
    int isf32 = *flagp;
    int b = blockIdx.x & 7;
    size_t rowbase = (size_t)b * SEQ;
    f32x4 zf = {0.f, 0.f, 0.f, 0.f};

    if (blockIdx.x < 8) {
        // ---------------- GRU ----------------
        __shared__ __align__(16) short H[2][16][136];   // 272B row stride (16B-mult, bank-spread)
        int tid = threadIdx.x, lane = tid & 63, w = tid >> 6;
        int col = lane & 15, quad = lane >> 4;
        for (int i = tid; i < 2 * 16 * 136; i += 256) ((short*)H)[i] = 0;
        // static B-fragments: Whh[n][k], n = (w+4l)*16+col, k = c*32+quad*8+e
        bf16x8 Bf[6][4];
#pragma unroll
        for (int l = 0; l < 6; l++) {
            int n = (w + 4 * l) * 16 + col;
#pragma unroll
            for (int c = 0; c < 4; c++) {
                int k0 = c * 32 + quad * 8;
                bf16x8 v;
#pragma unroll
                for (int e = 0; e < 8; e++)
                    v[e] = (short)f2bf(ldin(Whh, (size_t)n * 128 + k0 + e, isf32));
                Bf[l][c] = v;
            }
        }
        bool gl = (quad == 0);      // lanes 0-15 own valid C row 0
        float bias_r[2], bias_z[2], bias_n[2], hprev[2];
        float ir[2], iz[2], inn[2];
#pragma unroll
        for (int p2 = 0; p2 < 2; p2++) {
            int o = (w + 4 * p2) * 16 + col;
            bias_r[p2] = ldin(bhh, o, isf32);
            bias_z[p2] = ldin(bhh, 128 + o, isf32);
            bias_n[p2] = ldin(bhh, 256 + o, isf32);
            hprev[p2] = 0.f;
            if (gl) {
                size_t base = rowbase * 384;
                ir[p2]  = bf2f(ihw[base + o]);
                iz[p2]  = bf2f(ihw[base + 128 + o]);
                inn[p2] = bf2f(ihw[base + 256 + o]);
            }
        }
        __syncthreads();
        int p = 0;
        for (int t = 0; t < SEQ; t++) {
            bf16x8 Af[4];
#pragma unroll
            for (int c = 0; c < 4; c++)
                Af[c] = *reinterpret_cast<const bf16x8*>(&H[p][col][c * 32 + quad * 8]);
            float nir[2], niz[2], nin[2];
            if (gl && t + 1 < SEQ) {
#pragma unroll
                for (int p2 = 0; p2 < 2; p2++) {
                    int o = (w + 4 * p2) * 16 + col;
                    size_t base = (rowbase + t + 1) * 384;
                    nir[p2] = bf2f(ihw[base + o]);
                    niz[p2] = bf2f(ihw[base + 128 + o]);
                    nin[p2] = bf2f(ihw[base + 256 + o]);
                }
            }
            f32x4 acc[6];
#pragma unroll
            for (int l = 0; l < 6; l++) acc[l] = zf;
#pragma unroll
            for (int l = 0; l < 6; l++)
#pragma unroll
                for (int c = 0; c < 4; c++)
                    acc[l] = __builtin_amdgcn_mfma_f32_16x16x32_bf16(Af[c], Bf[l][c], acc[l], 0, 0, 0);
            if (gl) {
#pragma unroll
                for (int p2 = 0; p2 < 2; p2++) {
                    int o = (w + 4 * p2) * 16 + col;
                    float r  = sigf(ir[p2]  + acc[p2][0]     + bias_r[p2]);
                    float zg = sigf(iz[p2]  + acc[2 + p2][0] + bias_z[p2]);
                    float n  = tanhf_fast(inn[p2] + r * (acc[4 + p2][0] + bias_n[p2]));
                    float hnew = (1.f - zg) * n + zg * hprev[p2];
                    hprev[p2] = hnew;
                    unsigned short hb = f2bf(hnew);
                    H[p ^ 1][0][o] = (short)hb;
                    hrw[(rowbase + t) * 128 + o] = hb;
                }
            }
            __syncthreads();
            if (gl) {
#pragma unroll
                for (int p2 = 0; p2 < 2; p2++) { ir[p2] = nir[p2]; iz[p2] = niz[p2]; inn[p2] = nin[p2]; }
            }
            p ^= 1;
        }
    } else {
        // ---------------- SSM (wave 0 only) ----------------
        if (threadIdx.x >= 64) return;
        int lane = threadIdx.x, col = lane & 15, quad = lane >> 4;
        __shared__ __align__(16) short Hs[2][16][72];   // 144B stride (16B-mult)
        for (int i = lane; i < 2 * 16 * 72; i += 64) ((short*)Hs)[i] = 0;
        bf16x8 Bf[4][2];
#pragma unroll
        for (int l = 0; l < 4; l++) {
            int n = l * 16 + col;
#pragma unroll
            for (int c = 0; c < 2; c++) {
                int k0 = c * 32 + quad * 8;
                bf16x8 v;
#pragma unroll
                for (int e = 0; e < 8; e++)
                    v[e] = (short)f2bf(ldin(Amat, (size_t)n * 64 + k0 + e, isf32));
                Bf[l][c] = v;
            }
        }
        bool gl = (quad == 0);
        float bx[4], nbx[4];
        if (gl)
#pragma unroll
            for (int l = 0; l < 4; l++) bx[l] = bf2f(bxw[rowbase * 64 + l * 16 + col]);
        asm volatile("s_waitcnt lgkmcnt(0)" ::: "memory");
        int p = 0;
        for (int t = 0; t < SEQ; t++) {
            bf16x8 Af[2];
#pragma unroll
            for (int c = 0; c < 2; c++)
                Af[c] = *reinterpret_cast<const bf16x8*>(&Hs[p][col][c * 32 + quad * 8]);
            if (gl && t + 1 < SEQ)
#pragma unroll
                for (int l = 0; l < 4; l++) nbx[l] = bf2f(bxw[(rowbase + t + 1) * 64 + l * 16 + col]);
            f32x4 acc[4];
#pragma unroll
            for (int l = 0; l < 4; l++) acc[l] = zf;
#pragma unroll
            for (int l = 0; l < 4; l++)
#pragma unroll
                for (int c = 0; c < 2; c++)
                    acc[l] = __builtin_amdgcn_mfma_f32_16x16x32_bf16(Af[c], Bf[l][c], acc[l], 0, 0, 0);
            if (gl) {
#pragma unroll
                for (int l = 0; l < 4; l++) {
                    int o = l * 16 + col;
                    float v = acc[l][0] + bx[l];
                    float hv = v * sigf(v);
                    unsigned short hb = f2bf(hv);
                    Hs[p ^ 1][0][o] = (short)hb;
                    hsw[(rowbase + t) * 64 + o] = hb;
                }
            }
            asm volatile("s_waitcnt lgkmcnt(0)" ::: "memory");
            if (gl)
#pragma unroll
                for (int l = 0; l < 4; l++) bx[l] = nbx[l];
            p ^= 1;
        }
    }
}

// out[row,col] = g0*(x.Dw^T + hs.Cw^T + Cb + Db) + g1*(hr.pw^T + pb) — f32 store
__global__ __launch_bounds__(256) void out_kernel(
    const void* __restrict__ x,  const void* __restrict__ Dw, const void* __restrict__ Db,
    const unsigned short* __restrict__ hs, const void* __restrict__ Cw, const void* __restrict__ Cb,
    const unsigned short* __restrict__ hr, const void* __restrict__ pw, const void* __restrict__ pb,
    const float* __restrict__ gx, float* __restrict__ out,
    const int* __restrict__ flagp) {
    __shared__ __align__(16) short As[128][40];
    __shared__ __align__(16) short Bs[128][40];
    int isf32 = *flagp;
    int tid = threadIdx.x, lane = tid & 63, wave = tid >> 6;
    int wm = (wave >> 1) << 6, wn = (wave & 1) << 6;
    int tileM = blockIdx.x << 7, tileN = blockIdx.y << 7;
    f32x4 z = {0.f, 0.f, 0.f, 0.f};
    f32x4 acc1[4][4], acc2[4][4];
#pragma unroll
    for (int i = 0; i < 4; i++)
#pragma unroll
        for (int j = 0; j < 4; j++) { acc1[i][j] = z; acc2[i][j] = z; }

    for (int kb = 0; kb < 1024; kb += 32) {        // x . Dw^T
        __syncthreads();
        stage_tile(x,  1024, tileM, MROWS - 1, kb, As, tid, isf32);
        stage_tile(Dw, 1024, tileN, 1023, kb, Bs, tid, isf32);
        __syncthreads();
        mfma_tiles(As, Bs, wm, wn, lane, acc1);
    }
    for (int kb = 0; kb < 64; kb += 32) {          // + hs . Cw^T, same acc
        __syncthreads();
        stage_tile(hs, 64, tileM, MROWS - 1, kb, As, tid, 0);
        stage_tile(Cw, 64, tileN, 1023, kb, Bs, tid, isf32);
        __syncthreads();
        mfma_tiles(As, Bs, wm, wn, lane, acc1);
    }
    for (int kb = 0; kb < 128; kb += 32) {         // hr . pw^T
        __syncthreads();
        stage_tile(hr, 128, tileM, MROWS - 1, kb, As, tid, 0);
        stage_tile(pw, 128, tileN, 1023, kb, Bs, tid, isf32);
        __syncthreads();
        mfma_tiles(As, Bs, wm, wn, lane, acc2);
    }
#pragma unroll
    for (int i = 0; i < 4; i++) {
        int r0 = tileM + wm + i * 16 + ((lane >> 4) << 2);
#pragma unroll
        for (int j = 0; j < 4; j++) {
            int col = tileN + wn + j * 16 + (lane & 15);
            float cb  = ldin(Cb, col, isf32) + ldin(Db, col, isf32);
            float pbv = ldin(pb, col, isf32);
#pragma unroll
            for (int r = 0; r < 4; r++) {
                int row = r0 + r;
                float g0 = gx[row * 2], g1 = gx[row * 2 + 1];
                out[(size_t)row * 1024 + col] =
                    g0 * (acc1[i][j][r] + cb) + g1 * (acc2[i][j][r] + pbv);
            }
        }
    }
}

extern "C" void kernel_launch(void* const* d_in, const int* in_sizes, int n_in,
                              void* d_out, int out_size, void* d_ws, size_t ws_size,
                              hipStream_t stream) {
    static const int expect_sizes[16] = {16777216, 4096, 65536, 64, 65536, 1024,
                                         1048576, 1024, 393216, 384, 49152, 384,
                                         131072, 1024, 2048, 2};
    bool order_ok = (n_in == 16);
    if (order_ok)
        for (int i = 0; i < 16; i++)
            if (in_sizes[i] != expect_sizes[i]) { order_ok = false; break; }
    float* out = (float*)d_out;
    if (!order_ok) {
        zero_out_kernel<<<dim3(4096), dim3(256), 0, stream>>>(out);
        return;
    }

    const void* x    = d_in[0];
    const void* Amat = d_in[1];
    const void* Bw   = d_in[2];
    const void* Bb   = d_in[3];
    const void* Cw   = d_in[4];
    const void* Cb   = d_in[5];
    const void* Dw   = d_in[6];
    const void* Db   = d_in[7];
    const void* Wih  = d_in[8];
    const void* bih  = d_in[9];
    const void* Whh  = d_in[10];
    const void* bhh  = d_in[11];
    const void* pw   = d_in[12];
    const void* pb   = d_in[13];
    const void* gw   = d_in[14];
    const void* gb   = d_in[15];

    // d_ws (21.1 MB): flag | gx | hs | hr | bx | ih
    char* ws = (char*)d_ws;
    int*            flg = (int*)(ws);                        //       256 B
    float*          gxw = (float*)(ws + 256);                //   131,072 B
    unsigned short* hsw = (unsigned short*)(ws + 131328);    // 2,097,152 B
    unsigned short* hrw = (unsigned short*)(ws + 2228480);   // 4,194,304 B
    unsigned short* bxw = (unsigned short*)(ws + 6422784);   // 2,097,152 B
    unsigned short* ihw = (unsigned short*)(ws + 8519936);   // 12,582,912 B

    dim3 blk(256);
    sniff_kernel<<<dim3(1), dim3(64), 0, stream>>>((const unsigned short*)x, flg);
    gemm_bt_kernel<<<dim3(128, 3), blk, 0, stream>>>(x, Wih, bih, ihw, MROWS, 384, 1024, flg);
    gemm_bt_kernel<<<dim3(128, 1), blk, 0, stream>>>(x, Bw, Bb, bxw, MROWS, 64, 1024, flg);
    gate_kernel<<<dim3(4096), blk, 0, stream>>>(x, gw, gb, gxw, flg);
    scan_kernel<<<dim3(16), blk, 0, stream>>>(Amat, Whh, bhh, bxw, ihw, hsw, hrw, flg);
    out_kernel<<<dim3(128, 8), blk, 0, stream>>>(x, Dw, Db, hsw, Cw, Cb, hrw, pw, pb, gxw, out, flg);
}